// Round 1
// baseline (624.364 us; speedup 1.0000x reference)
//
#include <hip/hip_runtime.h>
#include <hip/hip_bf16.h>

#define B_ 8
#define NH_ 12
#define T_ 1024
#define D_ 256
#define QBLK 64
#define KVBLK 64
#define NQT (T_/QBLK)        // 16
#define NKV (T_/KVBLK)       // 16
#define NBLK (B_*NH_*NQT)    // 1536

typedef __attribute__((ext_vector_type(8))) short bf16x8;
typedef __attribute__((ext_vector_type(4))) float f32x4;

__device__ __forceinline__ short f2bf(float x) {
  __hip_bfloat16 h = __float2bfloat16(x);
  return *reinterpret_cast<short*>(&h);
}
__device__ __forceinline__ float bf2f(short x) {
  __hip_bfloat16 h = *reinterpret_cast<__hip_bfloat16*>(&x);
  return __bfloat162float(h);
}

// tab[t][i] = (cos, sin) of (frac(t * freqs[2i]) * 2*pi), i = n/2 (pairs share freq)
__global__ void build_tables_kernel(const float* __restrict__ freqs,
                                    float2* __restrict__ tab) {
  int idx = blockIdx.x * blockDim.x + threadIdx.x;
  if (idx >= T_ * (D_/2)) return;
  int t = idx >> 7;        // / 128
  int i = idx & 127;
  float ph = (float)t * freqs[2*i];
  ph -= floorf(ph);
  float ang = ph * 6.283185307179586f;
  tab[idx] = make_float2(cosf(ang), sinf(ang));
}

__global__ __launch_bounds__(256, 2)
void attn_kernel(const float* __restrict__ Q, const float* __restrict__ V,
                 const float2* __restrict__ tab, float* __restrict__ O) {
  // XCD-bijective swizzle: NBLK = 1536 = 8 * 192
  int bid = blockIdx.x;
  int swz = (bid & 7) * (NBLK / 8) + (bid >> 3);
  int qt = swz & (NQT - 1);
  int bh = swz >> 4;       // / NQT

  const float* __restrict__ Qbh = Q + (size_t)bh * T_ * D_;
  const float* __restrict__ Vbh = V + (size_t)bh * T_ * D_;
  float* __restrict__ Obh = O + (size_t)bh * T_ * D_;

  const int tid  = threadIdx.x;
  const int lane = tid & 63;
  const int wave = tid >> 6;   // 0..3
  const int grp  = lane >> 4;  // 0..3
  const int l16  = lane & 15;

  // 32KB + 32KB = 64KB static LDS; Pt aliases the first 8KB of Kt (per-wave 2KB)
  __shared__ __align__(16) unsigned short Kt[KVBLK * D_];  // roped K, bf16, swizzled [s][k]
  __shared__ __align__(16) unsigned short Vt[D_ * KVBLK];  // V^T,      bf16, swizzled [d][s]
  unsigned short* Pt = Kt + wave * (16 * KVBLK);

  // ---- Q fragments: 16 rows per wave, roped + pre-scaled by 1/sqrt(D)=1/16 ----
  bf16x8 qf[8];
  {
    int row = qt * QBLK + wave * 16 + l16;
    const float* qrow = Qbh + (size_t)row * D_;
    const float2* trow = tab + row * (D_/2);
#pragma unroll
    for (int kk = 0; kk < 8; ++kk) {
      int k0 = kk * 32 + grp * 8;
      float4 x0 = *(const float4*)(qrow + k0);
      float4 x1 = *(const float4*)(qrow + k0 + 4);
      float2 c0 = trow[k0/2], c1 = trow[k0/2+1], c2 = trow[k0/2+2], c3 = trow[k0/2+3];
      bf16x8 f;
      f[0] = f2bf((x0.x * c0.x - x0.y * c0.y) * 0.0625f);
      f[1] = f2bf((x0.y * c0.x + x0.x * c0.y) * 0.0625f);
      f[2] = f2bf((x0.z * c1.x - x0.w * c1.y) * 0.0625f);
      f[3] = f2bf((x0.w * c1.x + x0.z * c1.y) * 0.0625f);
      f[4] = f2bf((x1.x * c2.x - x1.y * c2.y) * 0.0625f);
      f[5] = f2bf((x1.y * c2.x + x1.x * c2.y) * 0.0625f);
      f[6] = f2bf((x1.z * c3.x - x1.w * c3.y) * 0.0625f);
      f[7] = f2bf((x1.w * c3.x + x1.z * c3.y) * 0.0625f);
      qf[kk] = f;
    }
  }

  f32x4 oacc[16];
#pragma unroll
  for (int dt = 0; dt < 16; ++dt) oacc[dt] = (f32x4){0.f, 0.f, 0.f, 0.f};
  float mrow[4] = {-1e30f, -1e30f, -1e30f, -1e30f};
  float lrow[4] = {0.f, 0.f, 0.f, 0.f};

  for (int kv = 0; kv < NKV; ++kv) {
    const int s0 = kv * KVBLK;
    __syncthreads();  // previous tile (incl. Pt alias of Kt) fully consumed

    // ---- stage K tile: rope(Q rows), bf16, swizzled ----
#pragma unroll
    for (int it = 0; it < 8; ++it) {
      int c = tid + it * 256;
      int row = c >> 5;     // 0..63
      int col8 = c & 31;    // 8-elem chunk
      int s = s0 + row;
      const float* src = Qbh + (size_t)s * D_ + col8 * 8;
      float4 x0 = *(const float4*)src;
      float4 x1 = *(const float4*)(src + 4);
      const float2* trow = tab + s * (D_/2) + col8 * 4;
      float2 c0 = trow[0], c1 = trow[1], c2 = trow[2], c3 = trow[3];
      bf16x8 kf;
      kf[0] = f2bf(x0.x * c0.x - x0.y * c0.y);
      kf[1] = f2bf(x0.y * c0.x + x0.x * c0.y);
      kf[2] = f2bf(x0.z * c1.x - x0.w * c1.y);
      kf[3] = f2bf(x0.w * c1.x + x0.z * c1.y);
      kf[4] = f2bf(x1.x * c2.x - x1.y * c2.y);
      kf[5] = f2bf(x1.y * c2.x + x1.x * c2.y);
      kf[6] = f2bf(x1.z * c3.x - x1.w * c3.y);
      kf[7] = f2bf(x1.w * c3.x + x1.z * c3.y);
      *(bf16x8*)&Kt[row * D_ + ((col8 * 8) ^ ((row & 7) << 3))] = kf;
    }
    // ---- stage V tile transposed [d][s], bf16, swizzled ----
    {
      int d = tid;  // 0..255
#pragma unroll
      for (int i8 = 0; i8 < 8; ++i8) {
        bf16x8 vv;
#pragma unroll
        for (int j = 0; j < 8; ++j)
          vv[j] = f2bf(Vbh[(size_t)(s0 + i8 * 8 + j) * D_ + d]);
        *(bf16x8*)&Vt[d * KVBLK + ((i8 * 8) ^ ((d & 7) << 3))] = vv;
      }
    }
    __syncthreads();

    // ---- S = (Q/16) K^T : 16x64 per wave ----
    f32x4 sacc[4];
#pragma unroll
    for (int st = 0; st < 4; ++st) {
      f32x4 a = {0.f, 0.f, 0.f, 0.f};
      int srow = st * 16 + l16;
#pragma unroll
      for (int kk = 0; kk < 8; ++kk) {
        bf16x8 kfr = *(const bf16x8*)&Kt[srow * D_ + ((kk * 32 + grp * 8) ^ ((srow & 7) << 3))];
        a = __builtin_amdgcn_mfma_f32_16x16x32_bf16(qf[kk], kfr, a, 0, 0, 0);
      }
      sacc[st] = a;
    }

    // ---- online softmax (row r = grp*4 + j, cols across l16 x 4 subtiles) ----
    short pb[16];
    float corr[4];
#pragma unroll
    for (int j = 0; j < 4; ++j) {
      float v = fmaxf(fmaxf(sacc[0][j], sacc[1][j]), fmaxf(sacc[2][j], sacc[3][j]));
      v = fmaxf(v, __shfl_xor(v, 1));
      v = fmaxf(v, __shfl_xor(v, 2));
      v = fmaxf(v, __shfl_xor(v, 4));
      v = fmaxf(v, __shfl_xor(v, 8));
      float nm = fmaxf(mrow[j], v);
      corr[j] = __expf(mrow[j] - nm);
      mrow[j] = nm;
      float ps = 0.f;
#pragma unroll
      for (int st = 0; st < 4; ++st) {
        float p = __expf(sacc[st][j] - nm);
        short b = f2bf(p);          // round once; sum the rounded value so
        pb[st * 4 + j] = b;         // normalization matches what PV consumes
        ps += bf2f(b);
      }
      ps += __shfl_xor(ps, 1);
      ps += __shfl_xor(ps, 2);
      ps += __shfl_xor(ps, 4);
      ps += __shfl_xor(ps, 8);
      lrow[j] = lrow[j] * corr[j] + ps;
    }
#pragma unroll
    for (int dt = 0; dt < 16; ++dt) {
      oacc[dt][0] *= corr[0];
      oacc[dt][1] *= corr[1];
      oacc[dt][2] *= corr[2];
      oacc[dt][3] *= corr[3];
    }

    __syncthreads();  // all waves done reading Kt before Pt (alias) is written

    // ---- write P (bf16) to per-wave LDS, swizzled [q][s] ----
#pragma unroll
    for (int j = 0; j < 4; ++j) {
      int r = grp * 4 + j;
#pragma unroll
      for (int st = 0; st < 4; ++st)
        Pt[r * KVBLK + ((st * 16 + l16) ^ ((r & 7) << 3))] = pb[st * 4 + j];
    }

    // ---- O += P V ----
#pragma unroll
    for (int kk2 = 0; kk2 < 2; ++kk2) {
      bf16x8 pf = *(const bf16x8*)&Pt[l16 * KVBLK + ((kk2 * 32 + grp * 8) ^ ((l16 & 7) << 3))];
#pragma unroll
      for (int dt = 0; dt < 16; ++dt) {
        int d = dt * 16 + l16;
        bf16x8 vf = *(const bf16x8*)&Vt[d * KVBLK + ((kk2 * 32 + grp * 8) ^ ((d & 7) << 3))];
        oacc[dt] = __builtin_amdgcn_mfma_f32_16x16x32_bf16(pf, vf, oacc[dt], 0, 0, 0);
      }
    }
  }

  // ---- epilogue: normalize and store fp32 ----
  float inv[4];
#pragma unroll
  for (int j = 0; j < 4; ++j) inv[j] = 1.0f / lrow[j];
  const int orow0 = qt * QBLK + wave * 16 + grp * 4;
#pragma unroll
  for (int dt = 0; dt < 16; ++dt) {
#pragma unroll
    for (int j = 0; j < 4; ++j) {
      Obh[(size_t)(orow0 + j) * D_ + dt * 16 + l16] = oacc[dt][j] * inv[j];
    }
  }
}

extern "C" void kernel_launch(void* const* d_in, const int* in_sizes, int n_in,
                              void* d_out, int out_size, void* d_ws, size_t ws_size,
                              hipStream_t stream) {
  const float* Q     = (const float*)d_in[0];
  const float* V     = (const float*)d_in[1];
  const float* freqs = (const float*)d_in[2];
  float* Out = (float*)d_out;
  float2* tab = (float2*)d_ws;  // T_*(D_/2)*sizeof(float2) = 1 MB

  build_tables_kernel<<<(T_ * (D_/2) + 255) / 256, 256, 0, stream>>>(freqs, tab);
  attn_kernel<<<NBLK, 256, 0, stream>>>(Q, V, tab, Out);
}

// Round 2
// 446.799 us; speedup vs baseline: 1.3974x; 1.3974x over previous
//
#include <hip/hip_runtime.h>
#include <hip/hip_bf16.h>
#include <stdint.h>

#define B_ 8
#define NH_ 12
#define NBH (B_*NH_)       // 96
#define T_ 1024
#define D_ 256
#define QBLK 128           // q rows per block (4 waves x 32)
#define QW 32              // q rows per wave
#define KVB 32             // kv tile
#define NKV (T_/KVB)       // 32
#define NQB (T_/QBLK)      // 8
#define NBLK (NBH*NQB)     // 768

typedef __attribute__((ext_vector_type(8))) short bf16x8;
typedef __attribute__((ext_vector_type(4))) short short4v;
typedef __attribute__((ext_vector_type(16))) float f32x16;
typedef unsigned short ushort_t;

#define Z16 ((f32x16){0,0,0,0,0,0,0,0,0,0,0,0,0,0,0,0})

__device__ __forceinline__ short f2bf(float x) {
  __hip_bfloat16 h = __float2bfloat16(x);
  return *reinterpret_cast<short*>(&h);
}
__device__ __forceinline__ float bf2f(short x) {
  __hip_bfloat16 h = *reinterpret_cast<__hip_bfloat16*>(&x);
  return __bfloat162float(h);
}
__device__ __forceinline__ void gload16(const ushort_t* g, ushort_t* l) {
  __builtin_amdgcn_global_load_lds(
      (const __attribute__((address_space(1))) uint32_t*)g,
      (__attribute__((address_space(3))) uint32_t*)l, 16, 0, 0);
}
__device__ __forceinline__ float hmax16(f32x16 v) {
  float a0 = fmaxf(v[0], v[1]),  a1 = fmaxf(v[2], v[3]);
  float a2 = fmaxf(v[4], v[5]),  a3 = fmaxf(v[6], v[7]);
  float a4 = fmaxf(v[8], v[9]),  a5 = fmaxf(v[10], v[11]);
  float a6 = fmaxf(v[12], v[13]), a7 = fmaxf(v[14], v[15]);
  float b0 = fmaxf(a0, a1), b1 = fmaxf(a2, a3), b2 = fmaxf(a4, a5), b3 = fmaxf(a6, a7);
  return fmaxf(fmaxf(b0, b1), fmaxf(b2, b3));
}

// ---------------- prep kernels ----------------

// tab[t][i] = (cos, sin) of (frac(t * freqs[2i]) * 2*pi)
__global__ void tab_kernel(const float* __restrict__ freqs, float2* __restrict__ tab) {
  int idx = blockIdx.x * blockDim.x + threadIdx.x;
  if (idx >= T_ * (D_/2)) return;
  int t = idx >> 7;
  int i = idx & 127;
  float ph = (float)t * freqs[2*i];
  ph -= floorf(ph);
  float ang = ph * 6.283185307179586f;
  tab[idx] = make_float2(cosf(ang), sinf(ang));
}

// KR[row][d] = rope(Q)[row][d] * 0.25  (bf16). row = bh*T + t.
__global__ __launch_bounds__(256) void kr_kernel(const float* __restrict__ Q,
                                                 const float2* __restrict__ tab,
                                                 ushort_t* __restrict__ KR) {
  int row = blockIdx.x * 8 + (threadIdx.x >> 5);
  int d8  = threadIdx.x & 31;
  int t = row & (T_ - 1);
  const float* src = Q + (size_t)row * D_ + d8 * 8;
  float4 x0 = *(const float4*)src;
  float4 x1 = *(const float4*)(src + 4);
  const float2* tr = tab + t * (D_/2) + d8 * 4;
  float2 c0 = tr[0], c1 = tr[1], c2 = tr[2], c3 = tr[3];
  bf16x8 f;
  f[0] = f2bf((x0.x * c0.x - x0.y * c0.y) * 0.25f);
  f[1] = f2bf((x0.y * c0.x + x0.x * c0.y) * 0.25f);
  f[2] = f2bf((x0.z * c1.x - x0.w * c1.y) * 0.25f);
  f[3] = f2bf((x0.w * c1.x + x0.z * c1.y) * 0.25f);
  f[4] = f2bf((x1.x * c2.x - x1.y * c2.y) * 0.25f);
  f[5] = f2bf((x1.y * c2.x + x1.x * c2.y) * 0.25f);
  f[6] = f2bf((x1.z * c3.x - x1.w * c3.y) * 0.25f);
  f[7] = f2bf((x1.w * c3.x + x1.z * c3.y) * 0.25f);
  *(bf16x8*)(KR + (size_t)row * D_ + d8 * 8) = f;
}

// VT[bh][d][t] = bf16(V[bh][t][d]) via 64x64 LDS tile transpose
__global__ __launch_bounds__(256) void vt_kernel(const float* __restrict__ V,
                                                 ushort_t* __restrict__ VT) {
  int blk = blockIdx.x;
  int d64 = blk & 3, t64 = (blk >> 2) & 15, bh = blk >> 6;
  __shared__ ushort_t st[64][66];
  {
    int t = threadIdx.x >> 2, j = threadIdx.x & 3;
    const float* src = V + ((size_t)bh * T_ + t64 * 64 + t) * D_ + d64 * 64 + j * 16;
#pragma unroll
    for (int q2 = 0; q2 < 4; ++q2) {
      float4 x = *(const float4*)(src + q2 * 4);
      st[t][j*16 + q2*4 + 0] = (ushort_t)f2bf(x.x);
      st[t][j*16 + q2*4 + 1] = (ushort_t)f2bf(x.y);
      st[t][j*16 + q2*4 + 2] = (ushort_t)f2bf(x.z);
      st[t][j*16 + q2*4 + 3] = (ushort_t)f2bf(x.w);
    }
  }
  __syncthreads();
  {
    int d = threadIdx.x >> 2, tq = threadIdx.x & 3;
    bf16x8 a_, b_;
#pragma unroll
    for (int i = 0; i < 8; ++i) {
      a_[i] = (short)st[tq*16 + i][d];
      b_[i] = (short)st[tq*16 + 8 + i][d];
    }
    ushort_t* dst = VT + ((size_t)bh * D_ + d64*64 + d) * T_ + t64*64 + tq*16;
    *(bf16x8*)dst = a_;
    *(bf16x8*)(dst + 8) = b_;
  }
}

// ---------------- attention kernel ----------------
// One iteration of the kv loop. KC/VC: compute buffers. KN/VN: stage target.
// LDS layouts (16B-chunk XOR swizzle so all ds_read_b128 are conflict-free):
//   K tile [32 s][256 d]: chunk(s, c) holds global chunk (s, c ^ (s&7))
//   V tile [256 d][32 s]: chunk(d, c) holds global chunk (d, c ^ (d&3))
#define ATTN_ITER(TT, KC, VC, KN, VN)                                          \
  {                                                                            \
    const int tt_ = (TT);                                                      \
    if (tt_ + 1 < NKV) {                                                       \
      const ushort_t* Ks_ = KRb + (size_t)(tt_ + 1) * (KVB * D_);              \
      const ushort_t* Vs_ = VTb + (size_t)(tt_ + 1) * KVB;                     \
      _Pragma("unroll")                                                        \
      for (int i = 0; i < 4; ++i) {                                            \
        gload16(Ks_ + koff[i], &KN[((i * 4 + wv) * 64) * 8]);                  \
        gload16(Vs_ + voff[i], &VN[((i * 4 + wv) * 64) * 8]);                  \
      }                                                                        \
    }                                                                          \
    f32x16 sacc = Z16;                                                         \
    _Pragma("unroll")                                                          \
    for (int m = 0; m < 16; ++m) {                                             \
      bf16x8 kf = *(const bf16x8*)&KC[lo * 256 + (((2*m + hi) ^ (lo & 7)) * 8)]; \
      sacc = __builtin_amdgcn_mfma_f32_32x32x16_bf16(kf, qf[m], sacc, 0, 0, 0);\
    }                                                                          \
    float pm = hmax16(sacc);                                                   \
    pm = fmaxf(pm, __shfl_xor(pm, 32));                                        \
    if (!__all(pm <= mR + 8.0f)) {                                             \
      float nm_ = fmaxf(mR, pm);                                               \
      float corr_ = __expf(mR - nm_);                                          \
      mR = nm_;                                                                \
      lR *= corr_;                                                             \
      if (hi == 0) bcw[lo] = corr_;                                            \
      asm volatile("s_waitcnt lgkmcnt(0)" ::: "memory");                       \
      _Pragma("unroll")                                                        \
      for (int g2 = 0; g2 < 4; ++g2) {                                         \
        float4 cr_ = *(const float4*)&bcw[g2 * 8 + hi * 4];                    \
        _Pragma("unroll")                                                      \
        for (int dt = 0; dt < 8; ++dt) {                                       \
          oacc[dt][g2*4 + 0] *= cr_.x;                                         \
          oacc[dt][g2*4 + 1] *= cr_.y;                                         \
          oacc[dt][g2*4 + 2] *= cr_.z;                                         \
          oacc[dt][g2*4 + 3] *= cr_.w;                                         \
        }                                                                      \
      }                                                                        \
    }                                                                          \
    ushort_t pb_[16];                                                          \
    float pv_[16];                                                             \
    _Pragma("unroll")                                                          \
    for (int r = 0; r < 16; ++r) {                                             \
      float p_ = __expf(sacc[r] - mR);                                         \
      short b_ = f2bf(p_);                                                     \
      pb_[r] = (ushort_t)b_;                                                   \
      pv_[r] = bf2f(b_);                                                       \
    }                                                                          \
    float s0_ = (pv_[0] + pv_[1]) + (pv_[2] + pv_[3]);                         \
    float s1_ = (pv_[4] + pv_[5]) + (pv_[6] + pv_[7]);                         \
    float s2_ = (pv_[8] + pv_[9]) + (pv_[10] + pv_[11]);                       \
    float s3_ = (pv_[12] + pv_[13]) + (pv_[14] + pv_[15]);                     \
    float ps_ = (s0_ + s1_) + (s2_ + s3_);                                     \
    ps_ += __shfl_xor(ps_, 32);                                                \
    lR += ps_;                                                                 \
    _Pragma("unroll")                                                          \
    for (int a = 0; a < 4; ++a) {                                              \
      short4v w_ = { (short)pb_[4*a], (short)pb_[4*a+1],                       \
                     (short)pb_[4*a+2], (short)pb_[4*a+3] };                   \
      *(short4v*)&Ptw[lo * 32 + ((a ^ (lo & 3)) * 8) + hi * 4] = w_;           \
    }                                                                          \
    bf16x8 pf0_ = *(const bf16x8*)&Ptw[lo * 32 + ((hi ^ (lo & 3)) * 8)];       \
    bf16x8 pf1_ = *(const bf16x8*)&Ptw[lo * 32 + (((hi + 2) ^ (lo & 3)) * 8)]; \
    _Pragma("unroll")                                                          \
    for (int dt = 0; dt < 8; ++dt) {                                           \
      bf16x8 vf0_ = *(const bf16x8*)&VC[(dt*32 + lo) * 32 + ((hi ^ (lo & 3)) * 8)]; \
      oacc[dt] = __builtin_amdgcn_mfma_f32_32x32x16_bf16(pf0_, vf0_, oacc[dt], 0, 0, 0); \
      bf16x8 vf1_ = *(const bf16x8*)&VC[(dt*32 + lo) * 32 + (((hi + 2) ^ (lo & 3)) * 8)]; \
      oacc[dt] = __builtin_amdgcn_mfma_f32_32x32x16_bf16(pf1_, vf1_, oacc[dt], 0, 0, 0); \
    }                                                                          \
    __syncthreads();                                                           \
  }

__global__ __launch_bounds__(256, 2)
void attn2(const ushort_t* __restrict__ KR, const ushort_t* __restrict__ VT,
           float* __restrict__ O) {
  int bid = blockIdx.x;
  int swz = (bid & 7) * (NBLK / 8) + (bid >> 3);   // bijective: 768 % 8 == 0
  int qb = swz & (NQB - 1);
  int bh = swz >> 3;

  const ushort_t* __restrict__ KRb = KR + (size_t)bh * T_ * D_;
  const ushort_t* __restrict__ VTb = VT + (size_t)bh * D_ * T_;
  float* __restrict__ Ob = O + (size_t)bh * T_ * D_;

  const int tid = threadIdx.x, lane = tid & 63, wv = tid >> 6;
  const int lo = lane & 31, hi = lane >> 5;
  const int q0 = qb * QBLK + wv * QW;

  __shared__ __align__(16) ushort_t Kb0[KVB * D_];
  __shared__ __align__(16) ushort_t Kb1[KVB * D_];
  __shared__ __align__(16) ushort_t Vb0[D_ * KVB];
  __shared__ __align__(16) ushort_t Vb1[D_ * KVB];
  __shared__ __align__(16) ushort_t Pt[4][QW * KVB];
  __shared__ __align__(16) float bc[4][32];

  ushort_t* Ptw = Pt[wv];
  float* bcw = bc[wv];

  // stage address maps (per lane, constant across tiles)
  int koff[4], voff[4];
#pragma unroll
  for (int i = 0; i < 4; ++i) {
    int ch = (i * 4 + wv) * 64 + lane;
    int r = ch >> 5, c = ch & 31;
    koff[i] = r * 256 + ((c ^ (r & 7)) * 8);
    int d = ch >> 2, c2 = ch & 3;
    voff[i] = d * 1024 + ((c2 ^ (d & 3)) * 8);
  }

  // resident Q fragments (rows of KR; 1/4 scale pre-applied -> QK gives S/16)
  bf16x8 qf[16];
  {
    const ushort_t* qrow = KRb + (size_t)(q0 + lo) * D_ + hi * 8;
#pragma unroll
    for (int m = 0; m < 16; ++m) qf[m] = *(const bf16x8*)(qrow + m * 16);
  }

  f32x16 oacc[8];
#pragma unroll
  for (int dt = 0; dt < 8; ++dt) oacc[dt] = Z16;
  float mR = -1e30f, lR = 0.0f;

  // prologue: stage tile 0 into buffer 0
#pragma unroll
  for (int i = 0; i < 4; ++i) {
    gload16(KRb + koff[i], &Kb0[((i * 4 + wv) * 64) * 8]);
    gload16(VTb + voff[i], &Vb0[((i * 4 + wv) * 64) * 8]);
  }
  __syncthreads();

  for (int t = 0; t < NKV; t += 2) {
    ATTN_ITER(t,     Kb0, Vb0, Kb1, Vb1);
    ATTN_ITER(t + 1, Kb1, Vb1, Kb0, Vb0);
  }

  // epilogue: broadcast 1/l per q-row, normalize, store
  if (hi == 0) bcw[lo] = 1.0f / lR;
  asm volatile("s_waitcnt lgkmcnt(0)" ::: "memory");
#pragma unroll
  for (int g2 = 0; g2 < 4; ++g2) {
    float4 il = *(const float4*)&bcw[g2 * 8 + hi * 4];
#pragma unroll
    for (int j = 0; j < 4; ++j) {
      int r = g2 * 4 + j;
      int qr = j + 8 * g2 + 4 * hi;
      float sc = (j == 0) ? il.x : (j == 1) ? il.y : (j == 2) ? il.z : il.w;
#pragma unroll
      for (int dt = 0; dt < 8; ++dt)
        Ob[(size_t)(q0 + qr) * D_ + dt * 32 + lo] = oacc[dt][r] * sc;
    }
  }
}

extern "C" void kernel_launch(void* const* d_in, const int* in_sizes, int n_in,
                              void* d_out, int out_size, void* d_ws, size_t ws_size,
                              hipStream_t stream) {
  const float* Q     = (const float*)d_in[0];
  const float* V     = (const float*)d_in[1];
  const float* freqs = (const float*)d_in[2];
  float* Out = (float*)d_out;

  float2* tab  = (float2*)d_ws;                                   // 1 MB
  ushort_t* KR = (ushort_t*)((char*)d_ws + (1 << 20));            // 48 MB
  ushort_t* VT = (ushort_t*)((char*)d_ws + (1 << 20) + (size_t)NBH * T_ * D_ * 2);  // 48 MB

  tab_kernel<<<(T_ * (D_/2) + 255) / 256, 256, 0, stream>>>(freqs, tab);
  kr_kernel<<<NBH * T_ / 8, 256, 0, stream>>>(Q, tab, KR);
  vt_kernel<<<NBH * 16 * 4, 256, 0, stream>>>(V, VT);
  attn2<<<NBLK, 256, 0, stream>>>(KR, VT, Out);
}

// Round 3
// 408.601 us; speedup vs baseline: 1.5281x; 1.0935x over previous
//
#include <hip/hip_runtime.h>
#include <hip/hip_bf16.h>
#include <stdint.h>

#define B_ 8
#define NH_ 12
#define NBH (B_*NH_)       // 96
#define T_ 1024
#define D_ 256
#define QBLK 128           // q rows per block (4 waves x 32)
#define QW 32              // q rows per wave
#define KVB 32             // kv tile
#define NKV (T_/KVB)       // 32
#define NQB (T_/QBLK)      // 8
#define NBLK (NBH*NQB)     // 768

typedef __attribute__((ext_vector_type(8))) short bf16x8;
typedef __attribute__((ext_vector_type(16))) float f32x16;
typedef unsigned short ushort_t;

#define Z16 ((f32x16){0,0,0,0,0,0,0,0,0,0,0,0,0,0,0,0})

// KR pre-scale: 0.25 * sqrt(log2(e)) so that (KR.KR) = (S/sqrt(256)) * log2(e)
#define KSCALE 0.30028060218f

__device__ __forceinline__ short f2bf(float x) {
  __hip_bfloat16 h = __float2bfloat16(x);
  return *reinterpret_cast<short*>(&h);
}
__device__ __forceinline__ void gload16(const ushort_t* g, ushort_t* l) {
  __builtin_amdgcn_global_load_lds(
      (const __attribute__((address_space(1))) uint32_t*)g,
      (__attribute__((address_space(3))) uint32_t*)l, 16, 0, 0);
}
__device__ __forceinline__ float hmax16(f32x16 v) {
  float a0 = fmaxf(v[0], v[1]),  a1 = fmaxf(v[2], v[3]);
  float a2 = fmaxf(v[4], v[5]),  a3 = fmaxf(v[6], v[7]);
  float a4 = fmaxf(v[8], v[9]),  a5 = fmaxf(v[10], v[11]);
  float a6 = fmaxf(v[12], v[13]), a7 = fmaxf(v[14], v[15]);
  float b0 = fmaxf(a0, a1), b1 = fmaxf(a2, a3), b2 = fmaxf(a4, a5), b3 = fmaxf(a6, a7);
  return fmaxf(fmaxf(b0, b1), fmaxf(b2, b3));
}

// ---------------- prep kernels ----------------

__global__ void tab_kernel(const float* __restrict__ freqs, float2* __restrict__ tab) {
  int idx = blockIdx.x * blockDim.x + threadIdx.x;
  if (idx >= T_ * (D_/2)) return;
  int t = idx >> 7;
  int i = idx & 127;
  float ph = (float)t * freqs[2*i];
  ph -= floorf(ph);
  float ang = ph * 6.283185307179586f;
  tab[idx] = make_float2(cosf(ang), sinf(ang));
}

// KR[row][d] = rope(Q)[row][d] * KSCALE  (bf16). row = bh*T + t.
__global__ __launch_bounds__(256) void kr_kernel(const float* __restrict__ Q,
                                                 const float2* __restrict__ tab,
                                                 ushort_t* __restrict__ KR) {
  int row = blockIdx.x * 8 + (threadIdx.x >> 5);
  int d8  = threadIdx.x & 31;
  int t = row & (T_ - 1);
  const float* src = Q + (size_t)row * D_ + d8 * 8;
  float4 x0 = *(const float4*)src;
  float4 x1 = *(const float4*)(src + 4);
  const float2* tr = tab + t * (D_/2) + d8 * 4;
  float2 c0 = tr[0], c1 = tr[1], c2 = tr[2], c3 = tr[3];
  bf16x8 f;
  f[0] = f2bf((x0.x * c0.x - x0.y * c0.y) * KSCALE);
  f[1] = f2bf((x0.y * c0.x + x0.x * c0.y) * KSCALE);
  f[2] = f2bf((x0.z * c1.x - x0.w * c1.y) * KSCALE);
  f[3] = f2bf((x0.w * c1.x + x0.z * c1.y) * KSCALE);
  f[4] = f2bf((x1.x * c2.x - x1.y * c2.y) * KSCALE);
  f[5] = f2bf((x1.y * c2.x + x1.x * c2.y) * KSCALE);
  f[6] = f2bf((x1.z * c3.x - x1.w * c3.y) * KSCALE);
  f[7] = f2bf((x1.w * c3.x + x1.z * c3.y) * KSCALE);
  *(bf16x8*)(KR + (size_t)row * D_ + d8 * 8) = f;
}

// VT[bh][d][t] = bf16(V[bh][t][d]) via 64x64 LDS tile transpose
__global__ __launch_bounds__(256) void vt_kernel(const float* __restrict__ V,
                                                 ushort_t* __restrict__ VT) {
  int blk = blockIdx.x;
  int d64 = blk & 3, t64 = (blk >> 2) & 15, bh = blk >> 6;
  __shared__ ushort_t st[64][66];
  {
    int t = threadIdx.x >> 2, j = threadIdx.x & 3;
    const float* src = V + ((size_t)bh * T_ + t64 * 64 + t) * D_ + d64 * 64 + j * 16;
#pragma unroll
    for (int q2 = 0; q2 < 4; ++q2) {
      float4 x = *(const float4*)(src + q2 * 4);
      st[t][j*16 + q2*4 + 0] = (ushort_t)f2bf(x.x);
      st[t][j*16 + q2*4 + 1] = (ushort_t)f2bf(x.y);
      st[t][j*16 + q2*4 + 2] = (ushort_t)f2bf(x.z);
      st[t][j*16 + q2*4 + 3] = (ushort_t)f2bf(x.w);
    }
  }
  __syncthreads();
  {
    int d = threadIdx.x >> 2, tq = threadIdx.x & 3;
    bf16x8 a_, b_;
#pragma unroll
    for (int i = 0; i < 8; ++i) {
      a_[i] = (short)st[tq*16 + i][d];
      b_[i] = (short)st[tq*16 + 8 + i][d];
    }
    ushort_t* dst = VT + ((size_t)bh * D_ + d64*64 + d) * T_ + t64*64 + tq*16;
    *(bf16x8*)dst = a_;
    *(bf16x8*)(dst + 8) = b_;
  }
}

// ---------------- attention kernel ----------------
// LDS layouts (16B-chunk XOR swizzles; verified conflict-free per 8-lane clock group):
//   K tile [32 s][256 d]: stored chunk (s, c) holds data chunk (s, c ^ (s&7))
//   V tile [256 d][32 s]: stored chunk (d, c) holds data chunk (d, c ^ ((d>>1)&3))
// P never touches LDS: cvt_pk_bf16 + v_permlane32_swap build the PV A-fragment
// in-register (T12). QK uses 2 accumulator chains; MFMA clusters setprio-wrapped.
#define ATTN_ITER(TT, KC, VC, KN, VN)                                          \
  {                                                                            \
    const int tt_ = (TT);                                                      \
    if (tt_ + 1 < NKV) {                                                       \
      const ushort_t* Ks_ = KRb + (size_t)(tt_ + 1) * (KVB * D_);              \
      const ushort_t* Vs_ = VTb + (size_t)(tt_ + 1) * KVB;                     \
      _Pragma("unroll")                                                        \
      for (int i = 0; i < 4; ++i) {                                            \
        gload16(Ks_ + koff[i], &KN[((i * 4 + wv) * 64) * 8]);                  \
        gload16(Vs_ + voff[i], &VN[((i * 4 + wv) * 64) * 8]);                  \
      }                                                                        \
    }                                                                          \
    f32x16 s0_ = Z16, s1_ = Z16;                                               \
    __builtin_amdgcn_s_setprio(1);                                             \
    _Pragma("unroll")                                                          \
    for (int m = 0; m < 16; m += 2) {                                          \
      bf16x8 kfa_ = *(const bf16x8*)&KC[lo * 256 + (((2*m + hi)     ^ (lo & 7)) * 8)]; \
      bf16x8 kfb_ = *(const bf16x8*)&KC[lo * 256 + (((2*m + 2 + hi) ^ (lo & 7)) * 8)]; \
      s0_ = __builtin_amdgcn_mfma_f32_32x32x16_bf16(kfa_, qf[m],   s0_, 0, 0, 0); \
      s1_ = __builtin_amdgcn_mfma_f32_32x32x16_bf16(kfb_, qf[m+1], s1_, 0, 0, 0); \
    }                                                                          \
    __builtin_amdgcn_s_setprio(0);                                             \
    f32x16 sacc_ = s0_ + s1_;                                                  \
    float pm_ = hmax16(sacc_);                                                 \
    pm_ = fmaxf(pm_, __shfl_xor(pm_, 32));                                     \
    if (!__all(pm_ <= mR + 8.0f)) {                                            \
      float nm_ = fmaxf(mR, pm_);                                              \
      float corr_ = exp2f(mR - nm_);                                           \
      mR = nm_;                                                                \
      lR *= corr_;                                                             \
      if (hi == 0) bcw[lo] = corr_;                                            \
      asm volatile("s_waitcnt lgkmcnt(0)" ::: "memory");                       \
      _Pragma("unroll")                                                        \
      for (int g2 = 0; g2 < 4; ++g2) {                                         \
        float4 cr_ = *(const float4*)&bcw[g2 * 8 + hi * 4];                    \
        _Pragma("unroll")                                                      \
        for (int dt = 0; dt < 8; ++dt) {                                       \
          oacc[dt][g2*4 + 0] *= cr_.x;                                         \
          oacc[dt][g2*4 + 1] *= cr_.y;                                         \
          oacc[dt][g2*4 + 2] *= cr_.z;                                         \
          oacc[dt][g2*4 + 3] *= cr_.w;                                         \
        }                                                                      \
      }                                                                        \
    }                                                                          \
    float p_[16];                                                              \
    _Pragma("unroll")                                                          \
    for (int r = 0; r < 16; ++r) p_[r] = exp2f(sacc_[r] - mR);                 \
    float ps_ = (((p_[0]+p_[1]) + (p_[2]+p_[3])) + ((p_[4]+p_[5]) + (p_[6]+p_[7]))) \
              + (((p_[8]+p_[9]) + (p_[10]+p_[11])) + ((p_[12]+p_[13]) + (p_[14]+p_[15]))); \
    ps_ += __shfl_xor(ps_, 32);                                                \
    lR += ps_;                                                                 \
    unsigned int c00_, c01_, c10_, c11_, c20_, c21_, c30_, c31_;               \
    asm("v_cvt_pk_bf16_f32 %0, %1, %2" : "=v"(c00_) : "v"(p_[0]),  "v"(p_[1])); \
    asm("v_cvt_pk_bf16_f32 %0, %1, %2" : "=v"(c01_) : "v"(p_[2]),  "v"(p_[3])); \
    asm("v_cvt_pk_bf16_f32 %0, %1, %2" : "=v"(c10_) : "v"(p_[4]),  "v"(p_[5])); \
    asm("v_cvt_pk_bf16_f32 %0, %1, %2" : "=v"(c11_) : "v"(p_[6]),  "v"(p_[7])); \
    asm("v_cvt_pk_bf16_f32 %0, %1, %2" : "=v"(c20_) : "v"(p_[8]),  "v"(p_[9])); \
    asm("v_cvt_pk_bf16_f32 %0, %1, %2" : "=v"(c21_) : "v"(p_[10]), "v"(p_[11])); \
    asm("v_cvt_pk_bf16_f32 %0, %1, %2" : "=v"(c30_) : "v"(p_[12]), "v"(p_[13])); \
    asm("v_cvt_pk_bf16_f32 %0, %1, %2" : "=v"(c31_) : "v"(p_[14]), "v"(p_[15])); \
    asm("v_permlane32_swap_b32 %0, %1" : "+v"(c00_), "+v"(c10_));              \
    asm("v_permlane32_swap_b32 %0, %1" : "+v"(c01_), "+v"(c11_));              \
    asm("v_permlane32_swap_b32 %0, %1" : "+v"(c20_), "+v"(c30_));              \
    asm("v_permlane32_swap_b32 %0, %1" : "+v"(c21_), "+v"(c31_));              \
    bf16x8 pA_, pB_;                                                           \
    {                                                                          \
      union { unsigned int u[4]; bf16x8 v; } tA_, tB_;                         \
      tA_.u[0] = c00_; tA_.u[1] = c01_; tA_.u[2] = c10_; tA_.u[3] = c11_;      \
      tB_.u[0] = c20_; tB_.u[1] = c21_; tB_.u[2] = c30_; tB_.u[3] = c31_;      \
      pA_ = tA_.v; pB_ = tB_.v;                                                \
    }                                                                          \
    __builtin_amdgcn_s_setprio(1);                                             \
    _Pragma("unroll")                                                          \
    for (int dt = 0; dt < 8; ++dt) {                                           \
      bf16x8 vf0_ = *(const bf16x8*)&VC[(dt*32 + lo) * 32 + ((hi ^ vswz) * 8)]; \
      oacc[dt] = __builtin_amdgcn_mfma_f32_32x32x16_bf16(pA_, vf0_, oacc[dt], 0, 0, 0); \
      bf16x8 vf1_ = *(const bf16x8*)&VC[(dt*32 + lo) * 32 + (((2 + hi) ^ vswz) * 8)]; \
      oacc[dt] = __builtin_amdgcn_mfma_f32_32x32x16_bf16(pB_, vf1_, oacc[dt], 0, 0, 0); \
    }                                                                          \
    __builtin_amdgcn_s_setprio(0);                                             \
    __syncthreads();                                                           \
  }

__global__ __launch_bounds__(256, 2)
void attn3(const ushort_t* __restrict__ KR, const ushort_t* __restrict__ VT,
           float* __restrict__ O) {
  int bid = blockIdx.x;
  int swz = (bid & 7) * (NBLK / 8) + (bid >> 3);   // bijective: 768 % 8 == 0
  int qb = swz & (NQB - 1);
  int bh = swz >> 3;

  const ushort_t* __restrict__ KRb = KR + (size_t)bh * T_ * D_;
  const ushort_t* __restrict__ VTb = VT + (size_t)bh * D_ * T_;
  float* __restrict__ Ob = O + (size_t)bh * T_ * D_;

  const int tid = threadIdx.x, lane = tid & 63, wv = tid >> 6;
  const int lo = lane & 31, hi = lane >> 5;
  const int vswz = (lo >> 1) & 3;
  const int q0 = qb * QBLK + wv * QW;

  __shared__ __align__(16) ushort_t Kb0[KVB * D_];
  __shared__ __align__(16) ushort_t Kb1[KVB * D_];
  __shared__ __align__(16) ushort_t Vb0[D_ * KVB];
  __shared__ __align__(16) ushort_t Vb1[D_ * KVB];
  __shared__ __align__(16) float bc[4][32];

  float* bcw = bc[wv];

  // stage address maps (per lane, constant across tiles; inverse-swizzled source)
  int koff[4], voff[4];
#pragma unroll
  for (int i = 0; i < 4; ++i) {
    int ch = (i * 4 + wv) * 64 + lane;
    int r = ch >> 5, c = ch & 31;
    koff[i] = r * 256 + ((c ^ (r & 7)) * 8);
    int d = ch >> 2, c2 = ch & 3;
    voff[i] = d * 1024 + ((c2 ^ ((d >> 1) & 3)) * 8);
  }

  // resident Q fragments (rows of KR; KSCALE pre-applied on both operands)
  bf16x8 qf[16];
  {
    const ushort_t* qrow = KRb + (size_t)(q0 + lo) * D_ + hi * 8;
#pragma unroll
    for (int m = 0; m < 16; ++m) qf[m] = *(const bf16x8*)(qrow + m * 16);
  }

  f32x16 oacc[8];
#pragma unroll
  for (int dt = 0; dt < 8; ++dt) oacc[dt] = Z16;
  float mR = -1e30f, lR = 0.0f;

  // prologue: stage tile 0 into buffer 0
#pragma unroll
  for (int i = 0; i < 4; ++i) {
    gload16(KRb + koff[i], &Kb0[((i * 4 + wv) * 64) * 8]);
    gload16(VTb + voff[i], &Vb0[((i * 4 + wv) * 64) * 8]);
  }
  __syncthreads();

  for (int t = 0; t < NKV; t += 2) {
    ATTN_ITER(t,     Kb0, Vb0, Kb1, Vb1);
    ATTN_ITER(t + 1, Kb1, Vb1, Kb0, Vb0);
  }

  // epilogue: broadcast 1/l per q-row, normalize, store
  if (hi == 0) bcw[lo] = 1.0f / lR;
  asm volatile("s_waitcnt lgkmcnt(0)" ::: "memory");
#pragma unroll
  for (int g2 = 0; g2 < 4; ++g2) {
    float4 il = *(const float4*)&bcw[g2 * 8 + hi * 4];
#pragma unroll
    for (int j = 0; j < 4; ++j) {
      int r = g2 * 4 + j;
      int qr = j + 8 * g2 + 4 * hi;
      float sc = (j == 0) ? il.x : (j == 1) ? il.y : (j == 2) ? il.z : il.w;
#pragma unroll
      for (int dt = 0; dt < 8; ++dt)
        Ob[(size_t)(q0 + qr) * D_ + dt * 32 + lo] = oacc[dt][r] * sc;
    }
  }
}

extern "C" void kernel_launch(void* const* d_in, const int* in_sizes, int n_in,
                              void* d_out, int out_size, void* d_ws, size_t ws_size,
                              hipStream_t stream) {
  const float* Q     = (const float*)d_in[0];
  const float* V     = (const float*)d_in[1];
  const float* freqs = (const float*)d_in[2];
  float* Out = (float*)d_out;

  float2* tab  = (float2*)d_ws;                                   // 1 MB
  ushort_t* KR = (ushort_t*)((char*)d_ws + (1 << 20));            // 48 MB
  ushort_t* VT = (ushort_t*)((char*)d_ws + (1 << 20) + (size_t)NBH * T_ * D_ * 2);  // 48 MB

  tab_kernel<<<(T_ * (D_/2) + 255) / 256, 256, 0, stream>>>(freqs, tab);
  kr_kernel<<<NBH * T_ / 8, 256, 0, stream>>>(Q, tab, KR);
  vt_kernel<<<NBH * 16 * 4, 256, 0, stream>>>(V, VT);
  attn3<<<NBLK, 256, 0, stream>>>(KR, VT, Out);
}